// Round 1
// baseline (243.815 us; speedup 1.0000x reference)
//
#include <hip/hip_runtime.h>
#include <hip/hip_bf16.h>

// PointConv: N=32768 points, E=786432 edges (sorted by out_index), K<=64
// product[n][c][m] = sum_edges (x_in[src][c]/cnt) * celu(celu(pos_local@W1)@W2)[m]
// out[n][k] = product[n].flat(1024) @ W3[1024][64] + b3[k]

typedef __attribute__((ext_vector_type(8))) short short8;
typedef __attribute__((ext_vector_type(4))) float f32x4;

static __device__ __forceinline__ unsigned short f2bf(float f){
    unsigned int u = __float_as_uint(f);
    u += 0x7fff + ((u >> 16) & 1);     // round-to-nearest-even
    return (unsigned short)(u >> 16);
}

// ---------------- Kernel 0: segment boundaries from sorted out_index ---------
// seg_start[v] = first edge e with out_index[e] >= v ; seg_start[N] = E
__global__ void seg_kernel(const int* __restrict__ out_index,
                           int* __restrict__ seg_start, int E, int N)
{
    int e = blockIdx.x * blockDim.x + threadIdx.x;
    if (e >= E) return;
    int cur = out_index[e];
    if (e == 0) {
        for (int v = 0; v <= cur; ++v) seg_start[v] = 0;
    } else {
        int prev = out_index[e - 1];
        for (int v = prev + 1; v <= cur; ++v) seg_start[v] = e;
    }
    if (e == E - 1) {
        for (int v = cur + 1; v <= N; ++v) seg_start[v] = E;
    }
}

// ---------------- Kernel S: W3 -> bf16 in MFMA B-fragment layout -------------
// B-frag for mfma_f32_16x16x32_bf16: lane holds B[k = quad*8 + j][n = lane&15]
// stored as W3frag[((kk*4 + ntile)*64 + lane)*8 + j]
__global__ void prep_w3(const float* __restrict__ W3,
                        unsigned short* __restrict__ W3frag)
{
    int o = blockIdx.x * blockDim.x + threadIdx.x;   // 65536 elements
    int j    = o & 7;
    int lane = (o >> 3) & 63;
    int t    = (o >> 9) & 3;
    int kk   = o >> 11;
    int k = kk * 32 + (lane >> 4) * 8 + j;
    int n = t * 16 + (lane & 15);
    W3frag[o] = f2bf(W3[k * 64 + n]);
}

// ---------------- Kernel 1: per-point edge aggregation (fp32 VALU) -----------
// One wave per output point. lane = m (C_MID column); acc[c] c=0..15 (C_IN).
// Writes product as bf16 row-major [N][1024] (c*64+m) == MFMA A-frag rows.
__global__ __launch_bounds__(256) void agg_kernel(
    const float* __restrict__ x_in, const float* __restrict__ pos_in,
    const float* __restrict__ pos_out, const int* __restrict__ in_index,
    const int* __restrict__ seg_start, const float* __restrict__ W1,
    const float* __restrict__ W2, unsigned short* __restrict__ Pbf)
{
    int lane = threadIdx.x & 63;
    int n = blockIdx.x * 4 + (threadIdx.x >> 6);
    int c = lane & 15;

    // W1 column for h1[c] (lanes 16..63 mirror lanes 0..15 — harmless)
    float w1_0 = W1[c], w1_1 = W1[16 + c], w1_2 = W1[32 + c];
    // W2 column m = lane
    float w2r[16];
    #pragma unroll
    for (int j = 0; j < 16; ++j) w2r[j] = W2[j * 64 + lane];

    int e0 = seg_start[n], e1 = seg_start[n + 1];
    int cnt = e1 - e0;
    float inv = cnt > 0 ? 1.0f / (float)cnt : 0.0f;
    if (cnt > 64) e1 = e0 + 64;   // dense K=64 pad: extra edges dropped (count keeps full value)

    float po0 = pos_out[n * 3 + 0];
    float po1 = pos_out[n * 3 + 1];
    float po2 = pos_out[n * 3 + 2];

    float acc[16];
    #pragma unroll
    for (int i = 0; i < 16; ++i) acc[i] = 0.0f;

    for (int e = e0; e < e1; ++e) {
        int src = in_index[e];
        float p0 = pos_in[src * 3 + 0] - po0;
        float p1 = pos_in[src * 3 + 1] - po1;
        float p2 = pos_in[src * 3 + 2] - po2;
        // h1[c] on lane c (dup across quads)
        float h1 = p0 * w1_0 + p1 * w1_1 + p2 * w1_2;
        h1 = h1 > 0.0f ? h1 : (__expf(h1) - 1.0f);          // celu, alpha=1
        // h2[m] = sum_j celu(h1[j]) * W2[j][m]  via readlane broadcast
        float h2 = 0.0f;
        #pragma unroll
        for (int j = 0; j < 16; ++j) {
            float hj = __int_as_float(__builtin_amdgcn_readlane(__float_as_int(h1), j));
            h2 = fmaf(hj, w2r[j], h2);
        }
        h2 = h2 > 0.0f ? h2 : (__expf(h2) - 1.0f);          // celu -> M_e[m]
        // x contribution
        float xv = x_in[src * 16 + c] * inv;                // x[c] on lane c
        #pragma unroll
        for (int j = 0; j < 16; ++j) {
            float xj = __int_as_float(__builtin_amdgcn_readlane(__float_as_int(xv), j));
            acc[j] = fmaf(xj, h2, acc[j]);
        }
    }

    // store product[n][c][m]: element index c*64 + m, bf16, coalesced per c
    unsigned short* dst = Pbf + (size_t)n * 1024 + lane;
    #pragma unroll
    for (int i = 0; i < 16; ++i) dst[i * 64] = f2bf(acc[i]);
}

// ---------------- Kernel 2: out = Pbf @ W3 + b3 (bf16 MFMA) ------------------
// wave computes 16 points x 16 out-cols; K = 1024 in 32 steps of 32.
// A-frag: lane holds P[row = ptile*16 + (lane&15)][kk*32 + quad*8 + j] (16B contig)
// D: col = lane&15 (out), row = quad*4 + reg (point)   [verified layout]
__global__ __launch_bounds__(256) void gemm_kernel(
    const unsigned short* __restrict__ Pbf,
    const unsigned short* __restrict__ W3frag,
    const float* __restrict__ b3, float* __restrict__ out)
{
    int lane = threadIdx.x & 63;
    int w = blockIdx.x * 4 + (threadIdx.x >> 6);
    int ptile = w >> 2;
    int ntile = w & 3;
    int quad = lane >> 4;
    int r = lane & 15;

    const short8* Arow = (const short8*)(Pbf + (size_t)(ptile * 16 + r) * 1024 + quad * 8);
    const short8* Bp   = (const short8*)W3frag + (size_t)ntile * 64 + lane;

    f32x4 acc = {0.0f, 0.0f, 0.0f, 0.0f};
    #pragma unroll 4
    for (int kk = 0; kk < 32; ++kk) {
        short8 a = Arow[kk * 4];          // advance 32 bf16 per step
        short8 b = Bp[(size_t)kk * 256];  // (kk*4+ntile)*64 + lane short8s
        acc = __builtin_amdgcn_mfma_f32_16x16x32_bf16(a, b, acc, 0, 0, 0);
    }

    int outcol = ntile * 16 + r;
    float bias = b3[outcol];
    #pragma unroll
    for (int i = 0; i < 4; ++i) {
        int prow = ptile * 16 + quad * 4 + i;
        out[(size_t)prow * 64 + outcol] = acc[i] + bias;
    }
}

extern "C" void kernel_launch(void* const* d_in, const int* in_sizes, int n_in,
                              void* d_out, int out_size, void* d_ws, size_t ws_size,
                              hipStream_t stream)
{
    const float* x_in    = (const float*)d_in[0];
    const float* pos_in  = (const float*)d_in[1];
    const float* pos_out = (const float*)d_in[2];
    const int* in_index  = (const int*)d_in[3];
    const int* out_index = (const int*)d_in[4];
    const float* W1 = (const float*)d_in[5];
    const float* W2 = (const float*)d_in[6];
    const float* W3 = (const float*)d_in[7];
    const float* b3 = (const float*)d_in[8];

    int N = in_sizes[0] / 16;    // 32768
    int E = in_sizes[3];         // 786432
    float* out = (float*)d_out;

    // workspace layout
    char* ws = (char*)d_ws;
    unsigned short* Pbf = (unsigned short*)ws;                 // N*1024 bf16 = 64 MB
    size_t offA = (size_t)N * 1024 * 2;
    int* seg = (int*)(ws + offA);                              // (N+1) int32
    size_t offB = offA + (((size_t)(N + 1) * 4 + 255) & ~(size_t)255);
    unsigned short* W3frag = (unsigned short*)(ws + offB);     // 65536 bf16

    seg_kernel<<<(E + 255) / 256, 256, 0, stream>>>(out_index, seg, E, N);
    prep_w3<<<256, 256, 0, stream>>>(W3, W3frag);
    agg_kernel<<<N / 4, 256, 0, stream>>>(x_in, pos_in, pos_out, in_index, seg, W1, W2, Pbf);
    gemm_kernel<<<N / 16, 256, 0, stream>>>(Pbf, W3frag, b3, out);
}

// Round 2
// 205.569 us; speedup vs baseline: 1.1860x; 1.1860x over previous
//
#include <hip/hip_runtime.h>
#include <hip/hip_bf16.h>

// PointConv: N=32768 points, E=786432 edges (sorted by out_index), K<=64
// product[n][c][m] = inv_n * sum_edges x_in[src][c] * celu(celu(pos_local@W1)@W2)[m]
// out[n][k] = product[n].flat(1024) @ W3[1024][64] + b3[k]

typedef __attribute__((ext_vector_type(8))) short short8;
typedef __attribute__((ext_vector_type(4))) float f32x4;

static __device__ __forceinline__ unsigned short f2bf(float f){
    unsigned int u = __float_as_uint(f);
    u += 0x7fff + ((u >> 16) & 1);     // round-to-nearest-even
    return (unsigned short)(u >> 16);
}

static __device__ __forceinline__ float rdlane(float v, int l){
    return __int_as_float(__builtin_amdgcn_readlane(__float_as_int(v), l));
}

// ---------------- Kernel 0: segment boundaries from sorted out_index ---------
__global__ void seg_kernel(const int* __restrict__ out_index,
                           int* __restrict__ seg_start, int E, int N)
{
    int e = blockIdx.x * blockDim.x + threadIdx.x;
    if (e >= E) return;
    int cur = out_index[e];
    if (e == 0) {
        for (int v = 0; v <= cur; ++v) seg_start[v] = 0;
    } else {
        int prev = out_index[e - 1];
        for (int v = prev + 1; v <= cur; ++v) seg_start[v] = e;
    }
    if (e == E - 1) {
        for (int v = cur + 1; v <= N; ++v) seg_start[v] = E;
    }
}

// ---------------- Kernel S: W3 -> bf16 in MFMA B-fragment layout -------------
// stored as W3frag[((kk*4 + ntile)*64 + lane)*8 + j] = W3[k][n]
__global__ void prep_w3(const float* __restrict__ W3,
                        unsigned short* __restrict__ W3frag)
{
    int o = blockIdx.x * blockDim.x + threadIdx.x;   // 65536 elements
    int j    = o & 7;
    int lane = (o >> 3) & 63;
    int t    = (o >> 9) & 3;
    int kk   = o >> 11;
    int k = kk * 32 + (lane >> 4) * 8 + j;
    int n = t * 16 + (lane & 15);
    W3frag[o] = f2bf(W3[k * 64 + n]);
}

// ---------------- Kernel 1: per-point edge aggregation (fp32 VALU) -----------
// One wave per output point. lane = m (C_MID column); acc[c] c=0..15 (C_IN).
// All per-edge loads are wave-uniform -> forced scalar (SMEM) via readfirstlane.
__global__ __launch_bounds__(256) void agg_kernel(
    const float* __restrict__ x_in, const float* __restrict__ pos_in,
    const float* __restrict__ pos_out, const int* __restrict__ in_index,
    const int* __restrict__ seg_start, const float* __restrict__ W1,
    const float* __restrict__ W2, unsigned short* __restrict__ Pbf)
{
    int lane = threadIdx.x & 63;
    int n = __builtin_amdgcn_readfirstlane(blockIdx.x * 4 + (threadIdx.x >> 6));
    int c = lane & 15;

    // W1 column for h1[c] (lanes 16..63 mirror lanes 0..15 — harmless)
    float w1_0 = W1[c], w1_1 = W1[16 + c], w1_2 = W1[32 + c];
    // W2 column m = lane
    float w2r[16];
    #pragma unroll
    for (int j = 0; j < 16; ++j) w2r[j] = W2[j * 64 + lane];

    int e0 = __builtin_amdgcn_readfirstlane(seg_start[n]);
    int e1 = __builtin_amdgcn_readfirstlane(seg_start[n + 1]);
    int cnt = e1 - e0;
    float inv = cnt > 0 ? 1.0f / (float)cnt : 0.0f;
    if (cnt > 64) e1 = e0 + 64;   // dense K=64 pad: extra edges dropped

    float po0 = pos_out[n * 3 + 0];   // uniform addr -> scalar load, lives in VGPR copy
    float po1 = pos_out[n * 3 + 1];
    float po2 = pos_out[n * 3 + 2];

    float acc[16];
    #pragma unroll
    for (int i = 0; i < 16; ++i) acc[i] = 0.0f;

    for (int e = e0; e < e1; ++e) {
        int src = __builtin_amdgcn_readfirstlane(in_index[e]);
        const float* pp = pos_in + (size_t)src * 3;
        const float* xp = x_in + (size_t)src * 16;
        // uniform loads -> SMEM; values arrive in SGPRs
        float xj[16];
        #pragma unroll
        for (int j = 0; j < 16; ++j) xj[j] = xp[j];
        float p0 = pp[0] - po0;
        float p1 = pp[1] - po1;
        float p2 = pp[2] - po2;
        // h1[c] on lane c (dup across quads)
        float h1 = fmaf(p0, w1_0, fmaf(p1, w1_1, p2 * w1_2));
        h1 = h1 > 0.0f ? h1 : (__expf(h1) - 1.0f);          // celu, alpha=1
        // h2[m=lane] = sum_j celu(h1[j]) * W2[j][m], 4 partial chains for ILP
        float s0 = 0.f, s1 = 0.f, s2 = 0.f, s3 = 0.f;
        #pragma unroll
        for (int j = 0; j < 16; j += 4) {
            s0 = fmaf(rdlane(h1, j    ), w2r[j    ], s0);
            s1 = fmaf(rdlane(h1, j + 1), w2r[j + 1], s1);
            s2 = fmaf(rdlane(h1, j + 2), w2r[j + 2], s2);
            s3 = fmaf(rdlane(h1, j + 3), w2r[j + 3], s3);
        }
        float h2 = (s0 + s1) + (s2 + s3);
        h2 = h2 > 0.0f ? h2 : (__expf(h2) - 1.0f);          // celu -> M_e[m]
        // outer-product accumulate: xj are SGPRs -> no readlane needed
        #pragma unroll
        for (int j = 0; j < 16; ++j) acc[j] = fmaf(xj[j], h2, acc[j]);
    }

    // store product[n][c][m]: element index c*64 + m, bf16; inv applied once here
    unsigned short* dst = Pbf + (size_t)n * 1024 + lane;
    #pragma unroll
    for (int i = 0; i < 16; ++i) dst[i * 64] = f2bf(acc[i] * inv);
}

// ---------------- Kernel 2: out = Pbf @ W3 + b3 (bf16 MFMA) ------------------
__global__ __launch_bounds__(256) void gemm_kernel(
    const unsigned short* __restrict__ Pbf,
    const unsigned short* __restrict__ W3frag,
    const float* __restrict__ b3, float* __restrict__ out)
{
    int lane = threadIdx.x & 63;
    int w = blockIdx.x * 4 + (threadIdx.x >> 6);
    int ptile = w >> 2;
    int ntile = w & 3;
    int quad = lane >> 4;
    int r = lane & 15;

    const short8* Arow = (const short8*)(Pbf + (size_t)(ptile * 16 + r) * 1024 + quad * 8);
    const short8* Bp   = (const short8*)W3frag + (size_t)ntile * 64 + lane;

    f32x4 acc = {0.0f, 0.0f, 0.0f, 0.0f};
    #pragma unroll 4
    for (int kk = 0; kk < 32; ++kk) {
        short8 a = Arow[kk * 4];          // advance 32 bf16 per step
        short8 b = Bp[(size_t)kk * 256];  // (kk*4+ntile)*64 + lane short8s
        acc = __builtin_amdgcn_mfma_f32_16x16x32_bf16(a, b, acc, 0, 0, 0);
    }

    int outcol = ntile * 16 + r;
    float bias = b3[outcol];
    #pragma unroll
    for (int i = 0; i < 4; ++i) {
        int prow = ptile * 16 + quad * 4 + i;
        out[(size_t)prow * 64 + outcol] = acc[i] + bias;
    }
}

extern "C" void kernel_launch(void* const* d_in, const int* in_sizes, int n_in,
                              void* d_out, int out_size, void* d_ws, size_t ws_size,
                              hipStream_t stream)
{
    const float* x_in    = (const float*)d_in[0];
    const float* pos_in  = (const float*)d_in[1];
    const float* pos_out = (const float*)d_in[2];
    const int* in_index  = (const int*)d_in[3];
    const int* out_index = (const int*)d_in[4];
    const float* W1 = (const float*)d_in[5];
    const float* W2 = (const float*)d_in[6];
    const float* W3 = (const float*)d_in[7];
    const float* b3 = (const float*)d_in[8];

    int N = in_sizes[0] / 16;    // 32768
    int E = in_sizes[3];         // 786432
    float* out = (float*)d_out;

    // workspace layout
    char* ws = (char*)d_ws;
    unsigned short* Pbf = (unsigned short*)ws;                 // N*1024 bf16 = 64 MB
    size_t offA = (size_t)N * 1024 * 2;
    int* seg = (int*)(ws + offA);                              // (N+1) int32
    size_t offB = offA + (((size_t)(N + 1) * 4 + 255) & ~(size_t)255);
    unsigned short* W3frag = (unsigned short*)(ws + offB);     // 65536 bf16

    seg_kernel<<<(E + 255) / 256, 256, 0, stream>>>(out_index, seg, E, N);
    prep_w3<<<256, 256, 0, stream>>>(W3, W3frag);
    agg_kernel<<<N / 4, 256, 0, stream>>>(x_in, pos_in, pos_out, in_index, seg, W1, W2, Pbf);
    gemm_kernel<<<N / 16, 256, 0, stream>>>(Pbf, W3frag, b3, out);
}